// Round 15
// baseline (69.517 us; speedup 1.0000x reference)
//
#include <hip/hip_runtime.h>
#include <hip/hip_bf16.h>

// x:[16,64,128,128] f32 -> stats -> MLP -> per-sample kern[64,64,3,3] -> conv(pad=1)
// bf16 MFMA implicit GEMM.
// xT layout: [b][y][kp(2)][130 xi][32 ci] (x-padded zero cols) -- B-frag = one
// dense 1KB wave load from global (R14-verified).
// wT layout: [b][tap(9)][co(64)][64 ci, slot s at s^(co&7)] (R13-verified).
// R15: ONLY xpose changed (attribution experiment): 512-thr blocks, wave=cig,
// strip=4 rows, all 8 ci-groups of a 64B write chunk in ONE block (tight L2
// merge), 512 blocks = 16 waves/CU, shuffle-only stats (no LDS/barrier).
// part goes 16->32 partials; kern_gen loop adjusted. conv = R14 verbatim.

#define B_ 16
#define NPIX 16384
#define KEL 36864
#define XT_RS 8320          // shorts per y row = 2 kp * 130 xi * 32 ci

typedef __attribute__((ext_vector_type(4))) float f32x4;
typedef __attribute__((ext_vector_type(8))) short short8;

static __device__ __forceinline__ short bf16_of(float f) {
    __hip_bfloat16 h = __float2bfloat16(f);
    return *reinterpret_cast<short*>(&h);
}

// ---------- Kernel 1: transpose x -> xT bf16 [b][y][kp][130][32]; partial stats ----------
// grid (b=16, ys=32), 512 thr (8 waves). Wave w = ci-group w (8 ci). Strip = 4 rows.
// All 8 waves write the 8 interleaved 16B slots of each 64B chunk -> same-block L2 merge.
__global__ __launch_bounds__(512) void xpose_stats(const float* __restrict__ x,
                                                   short* __restrict__ xT,
                                                   float* __restrict__ part) {
    int b = blockIdx.x, ys = blockIdx.y;
    int t = threadIdx.x;
    int cig = t >> 6, l = t & 63;
    int kp = cig >> 2, c32 = (cig & 3) * 8;

    const float* xb = x + ((size_t)(b * 64 + cig * 8)) * NPIX;
    short* xTb = xT + (size_t)b * 128 * XT_RS;

    float s[8], ss[8];
    #pragma unroll
    for (int c = 0; c < 8; c++) { s[c] = 0.f; ss[c] = 0.f; }

    #pragma unroll
    for (int it = 0; it < 2; it++) {
        int y = ys * 4 + it * 2 + (l >> 5);
        int x0 = (l & 31) * 4;
        f32x4 v[8];
        #pragma unroll
        for (int c = 0; c < 8; c++) {
            v[c] = *(const f32x4*)(xb + (size_t)c * NPIX + y * 128 + x0);
            s[c]  += v[c][0] + v[c][1] + v[c][2] + v[c][3];
            ss[c] += v[c][0]*v[c][0] + v[c][1]*v[c][1] + v[c][2]*v[c][2] + v[c][3]*v[c][3];
        }
        #pragma unroll
        for (int xi = 0; xi < 4; xi++) {
            short8 o;
            #pragma unroll
            for (int c = 0; c < 8; c++) o[c] = bf16_of(v[c][xi]);
            *(short8*)(xTb + ((size_t)(y * 260 + kp * 130 + x0 + xi + 1)) * 32 + c32) = o;
        }
    }
    // zero-pad halo columns xi=0 and xi=129 for this strip (both kp, all c32)
    if (t < 64) {
        int y2 = ys * 4 + (t & 3);
        int col = (t & 4) ? 129 : 0;
        int kpz = (t >> 3) & 1;
        int c32z = ((t >> 4) & 3) * 8;
        short8 z = {0, 0, 0, 0, 0, 0, 0, 0};
        *(short8*)(xTb + ((size_t)(y2 * 260 + kpz * 130 + col)) * 32 + c32z) = z;
    }

    // in-wave reduction (64 lanes cover the whole strip for this cig)
    #pragma unroll
    for (int c = 0; c < 8; c++) {
        float a = s[c], q = ss[c];
        for (int off = 32; off; off >>= 1) { a += __shfl_down(a, off); q += __shfl_down(q, off); }
        s[c] = a; ss[c] = q;
    }
    if (l == 0) {
        float* pp = part + ((size_t)((b * 8 + cig) * 32 + ys)) * 16;
        #pragma unroll
        for (int c = 0; c < 8; c++) { pp[c * 2] = s[c]; pp[c * 2 + 1] = ss[c]; }
    }
}

// ---------- Kernel 2: w2 read once per j; grid 288, thread = (j, b-half) ----------
__global__ __launch_bounds__(256) void kern_gen(const float* __restrict__ part,
                                                const float* __restrict__ w1,
                                                const float* __restrict__ b1,
                                                const float* __restrict__ w2,
                                                const float* __restrict__ b2,
                                                short* __restrict__ wT) {
    __shared__ float st[16][128];
    __shared__ float hT[32][16];
    int t = threadIdx.x;

    for (int id = t; id < 1024; id += 256) {       // stats for all (b, ci)
        int b = id >> 6, ci = id & 63;
        const float* pb = part + ((size_t)((b * 8 + (ci >> 3)) * 32)) * 16 + (ci & 7) * 2;
        float s = 0.f, q = 0.f;
        #pragma unroll
        for (int p = 0; p < 32; p++) { s += pb[p * 16]; q += pb[p * 16 + 1]; }
        float mean = s * (1.f / NPIX);
        float var = fmaxf((q - s * mean) * (1.f / (NPIX - 1)), 0.f);
        st[b][ci] = mean;
        st[b][64 + ci] = sqrtf(var);
    }
    __syncthreads();
    for (int id = t; id < 512; id += 256) {        // h for all (b, 32), transposed
        int b = id >> 5, jj = id & 31;
        float acc = b1[jj];
        for (int i = 0; i < 128; i++) acc += st[b][i] * w1[i * 32 + jj];
        hT[jj][b] = fmaxf(acc, 0.f);
    }
    __syncthreads();

    int j = blockIdx.x * 128 + (t & 127);
    int bh = t >> 7;                               // b-half 0/1
    float wv[32];
    #pragma unroll
    for (int i = 0; i < 32; i++) wv[i] = w2[(size_t)i * KEL + j];
    float bv = b2[j];

    float acc[8];
    #pragma unroll
    for (int k = 0; k < 8; k++) acc[k] = bv;
    #pragma unroll
    for (int i = 0; i < 32; i++) {
        float wvi = wv[i];
        const f32x4* hr = (const f32x4*)&hT[i][bh * 8];
        #pragma unroll
        for (int q4 = 0; q4 < 2; q4++) {
            f32x4 hq = hr[q4];
            acc[q4 * 4 + 0] += hq[0] * wvi;
            acc[q4 * 4 + 1] += hq[1] * wvi;
            acc[q4 * 4 + 2] += hq[2] * wvi;
            acc[q4 * 4 + 3] += hq[3] * wvi;
        }
    }

    // j = (co*64+ci)*9 + tap; pre-swizzled: [tap][co][ (ci>>3)^(co&7) slot ]
    int co = j / 576;
    int rem = j - co * 576;
    int ci = rem / 9;
    int tap = rem - ci * 9;
    size_t dst = (size_t)tap * 4096 + co * 64 + ((((ci >> 3) ^ (co & 7)) << 3) | (ci & 7));
    #pragma unroll
    for (int k = 0; k < 8; k++)
        wT[(size_t)(bh * 8 + k) * KEL + dst] = bf16_of(acc[k]);
}

// ---------- Kernel 3: conv via MFMA, B-frags straight from global (R14 verbatim) ----------
__global__ __launch_bounds__(512, 4) void conv_mfma(const short* __restrict__ xT,
                                                    const short* __restrict__ wT,
                                                    float* __restrict__ out) {
    __shared__ __align__(16) short wls[9 * 512 * 8];    // slot = tap*512 + co*8 + s

    int b = blockIdx.x, xt = blockIdx.y, yo = blockIdx.z;
    int x0 = xt * 64, y0 = yo * 8;
    int t = threadIdx.x;
    int l = t & 63, w = t >> 6;
    int xq = w & 3, rh = w >> 2;
    int l15 = l & 15, lg = l >> 4;

    const short* xTb = xT + (size_t)b * 128 * XT_RS;
    const short* wTb = wT + (size_t)b * KEL;

    // ---- stage wls (pure linear DMA, wT pre-swizzled) ----
    #pragma unroll
    for (int it = 0; it < 9; it++) {
        __builtin_amdgcn_global_load_lds(
            (const __attribute__((address_space(1))) void*)(wTb + (size_t)(it * 512 + t) * 8),
            (__attribute__((address_space(3))) void*)(wls + (it * 512 + (t & ~63)) * 8),
            16, 0, 0);
    }
    asm volatile("s_waitcnt vmcnt(0)" ::: "memory");
    __syncthreads();

    int px = x0 + xq * 16 + l15;          // output pixel column (0..127)
    int yb = y0 + rh * 4;                 // wave's first output row

    f32x4 acc[4][4];                      // [row r][co-frag g]
    #pragma unroll
    for (int r = 0; r < 4; r++)
        #pragma unroll
        for (int g = 0; g < 4; g++) acc[r][g] = (f32x4){0.f, 0.f, 0.f, 0.f};

    #pragma unroll
    for (int kp = 0; kp < 2; kp++) {
        int pa = (kp * 4 + lg) ^ (l15 & 7);
        #pragma unroll
        for (int dx = 0; dx < 3; dx++) {
            // 6-row sliding B window: input rows yb-1 .. yb+4 at column px+dx
            short8 bf6[6];
            #pragma unroll
            for (int s = 0; s < 6; s++) {
                int yin = yb - 1 + s;
                short8 v = {0, 0, 0, 0, 0, 0, 0, 0};
                if ((unsigned)yin < 128u)
                    v = *(const short8*)(xTb + (size_t)yin * XT_RS
                            + (size_t)(kp * 130 + px + dx) * 32 + lg * 8);
                bf6[s] = v;
            }
            #pragma unroll
            for (int dy = 0; dy < 3; dy++) {
                int tap = dy * 3 + dx;
                short8 a[4];
                #pragma unroll
                for (int g = 0; g < 4; g++)
                    a[g] = *(const short8*)&wls[(tap * 512 + (g * 16 + l15) * 8 + pa) * 8];
                #pragma unroll
                for (int r = 0; r < 4; r++)
                    #pragma unroll
                    for (int g = 0; g < 4; g++)
                        acc[r][g] = __builtin_amdgcn_mfma_f32_16x16x32_bf16(a[g], bf6[r + dy], acc[r][g], 0, 0, 0);
            }
        }
    }

    // ---- store 4 co-frags x 4 regs x 4 rows ----
    #pragma unroll
    for (int g = 0; g < 4; g++) {
        float* ob = out + ((size_t)(b * 64 + g * 16 + lg * 4)) * NPIX + yb * 128 + px;
        #pragma unroll
        for (int reg = 0; reg < 4; reg++)
            #pragma unroll
            for (int r = 0; r < 4; r++)
                ob[(size_t)reg * NPIX + r * 128] = acc[r][g][reg];
    }
}

extern "C" void kernel_launch(void* const* d_in, const int* in_sizes, int n_in,
                              void* d_out, int out_size, void* d_ws, size_t ws_size,
                              hipStream_t stream) {
    const float* x  = (const float*)d_in[0];
    const float* w1 = (const float*)d_in[1];
    const float* b1 = (const float*)d_in[2];
    const float* w2 = (const float*)d_in[3];
    const float* b2 = (const float*)d_in[4];
    float* out = (float*)d_out;

    float* part = (float*)d_ws;                                   // 256 KB (16*8*32*16 f32)
    short* wT = (short*)((char*)d_ws + 262144);                   // 1.18 MB
    short* xT = (short*)((char*)d_ws + 262144 + 1179648);         // 34.1 MB

    xpose_stats<<<dim3(B_, 32), 512, 0, stream>>>(x, xT, part);
    kern_gen<<<dim3(288), 256, 0, stream>>>(part, w1, b1, w2, b2, wT);
    conv_mfma<<<dim3(B_, 2, 16), 512, 0, stream>>>(xT, wT, out);
}

// Round 16
// 69.344 us; speedup vs baseline: 1.0025x; 1.0025x over previous
//
#include <hip/hip_runtime.h>
#include <hip/hip_bf16.h>

// x:[16,64,128,128] f32 -> stats -> MLP -> per-sample kern[64,64,3,3] -> conv(pad=1)
// R16: NO transpose kernel. Stats = pure coalesced read. Conv stages x tiles
// DIRECTLY from NCHW f32 (VGPR cvt -> bf16 -> swizzled ds_write_b128), LDS
// image + compute loop = R13 verbatim (2 resident blocks/CU, weights in LDS).
// The R2-R15 xpose's strided-16B writes (~25% HBM write efficiency, ~28us)
// are eliminated entirely.
// wT layout: [b][tap(9)][co(64)][64 ci, slot s at s^(co&7)] (R13-verified).

#define B_ 16
#define NPIX 16384
#define KEL 36864

typedef __attribute__((ext_vector_type(4))) float f32x4;
typedef __attribute__((ext_vector_type(8))) short short8;

static __device__ __forceinline__ short bf16_of(float f) {
    __hip_bfloat16 h = __float2bfloat16(f);
    return *reinterpret_cast<short*>(&h);
}

// ---------- Kernel 1: per-(b,ci) partial stats (pure read, coalesced) ----------
// grid (b=16, cig=8, pt=16), 256 thr: 8 ci x 8 rows x 128 px.
__global__ __launch_bounds__(256) void stats_k(const float* __restrict__ x,
                                               float* __restrict__ part) {
    int b = blockIdx.x, cig = blockIdx.y, pt = blockIdx.z;
    int t = threadIdx.x;
    int y = pt * 8 + (t >> 5);
    int x0 = (t & 31) * 4;

    const float* xb = x + ((size_t)(b * 64 + cig * 8)) * NPIX;
    float s[8], ss[8];
    #pragma unroll
    for (int c = 0; c < 8; c++) {
        f32x4 v = *(const f32x4*)(xb + (size_t)c * NPIX + y * 128 + x0);
        s[c]  = v[0] + v[1] + v[2] + v[3];
        ss[c] = v[0]*v[0] + v[1]*v[1] + v[2]*v[2] + v[3]*v[3];
    }

    __shared__ float red[4][16];
    int lane = t & 63, w = t >> 6;
    #pragma unroll
    for (int c = 0; c < 8; c++) {
        float a = s[c], q = ss[c];
        for (int off = 32; off; off >>= 1) { a += __shfl_down(a, off); q += __shfl_down(q, off); }
        if (lane == 0) { red[w][c * 2] = a; red[w][c * 2 + 1] = q; }
    }
    __syncthreads();
    if (t < 16)
        part[((size_t)((b * 8 + cig) * 16 + pt)) * 16 + t] =
            red[0][t] + red[1][t] + red[2][t] + red[3][t];
}

// ---------- Kernel 2: w2 read once per j; grid 288, thread = (j, b-half) ----------
__global__ __launch_bounds__(256) void kern_gen(const float* __restrict__ part,
                                                const float* __restrict__ w1,
                                                const float* __restrict__ b1,
                                                const float* __restrict__ w2,
                                                const float* __restrict__ b2,
                                                short* __restrict__ wT) {
    __shared__ float st[16][128];
    __shared__ float hT[32][16];
    int t = threadIdx.x;

    for (int id = t; id < 1024; id += 256) {       // stats for all (b, ci)
        int b = id >> 6, ci = id & 63;
        const float* pb = part + ((size_t)((b * 8 + (ci >> 3)) * 16)) * 16 + (ci & 7) * 2;
        float s = 0.f, q = 0.f;
        #pragma unroll
        for (int p = 0; p < 16; p++) { s += pb[p * 16]; q += pb[p * 16 + 1]; }
        float mean = s * (1.f / NPIX);
        float var = fmaxf((q - s * mean) * (1.f / (NPIX - 1)), 0.f);
        st[b][ci] = mean;
        st[b][64 + ci] = sqrtf(var);
    }
    __syncthreads();
    for (int id = t; id < 512; id += 256) {        // h for all (b, 32), transposed
        int b = id >> 5, jj = id & 31;
        float acc = b1[jj];
        for (int i = 0; i < 128; i++) acc += st[b][i] * w1[i * 32 + jj];
        hT[jj][b] = fmaxf(acc, 0.f);
    }
    __syncthreads();

    int j = blockIdx.x * 128 + (t & 127);
    int bh = t >> 7;                               // b-half 0/1
    float wv[32];
    #pragma unroll
    for (int i = 0; i < 32; i++) wv[i] = w2[(size_t)i * KEL + j];
    float bv = b2[j];

    float acc[8];
    #pragma unroll
    for (int k = 0; k < 8; k++) acc[k] = bv;
    #pragma unroll
    for (int i = 0; i < 32; i++) {
        float wvi = wv[i];
        const f32x4* hr = (const f32x4*)&hT[i][bh * 8];
        #pragma unroll
        for (int q4 = 0; q4 < 2; q4++) {
            f32x4 hq = hr[q4];
            acc[q4 * 4 + 0] += hq[0] * wvi;
            acc[q4 * 4 + 1] += hq[1] * wvi;
            acc[q4 * 4 + 2] += hq[2] * wvi;
            acc[q4 * 4 + 3] += hq[3] * wvi;
        }
    }

    // j = (co*64+ci)*9 + tap; pre-swizzled: [tap][co][ (ci>>3)^(co&7) slot ]
    int co = j / 576;
    int rem = j - co * 576;
    int ci = rem / 9;
    int tap = rem - ci * 9;
    size_t dst = (size_t)tap * 4096 + co * 64 + ((((ci >> 3) ^ (co & 7)) << 3) | (ci & 7));
    #pragma unroll
    for (int k = 0; k < 8; k++)
        wT[(size_t)(bh * 8 + k) * KEL + dst] = bf16_of(acc[k]);
}

// ---------- Kernel 3: conv via MFMA; x staged DIRECTLY from NCHW f32 ----------
// grid (b=16, xt+4*cog=8, ys=16) = 2048 blocks (8/CU, 2 resident), 256 thr.
// Block: 32 px x 8 rows x 32 co. LDS: xls 10x272x16B (43520) + wls 9x256x16B
// (36864) = 80384 B. Staging: thread (xi,cig) loads 8 f32 (stride NPIX),
// cvt bf16, one swizzled ds_write_b128. Compute/store = R13 verbatim.
__global__ __launch_bounds__(256, 2) void conv_mfma(const float* __restrict__ x,
                                                    const short* __restrict__ wT,
                                                    float* __restrict__ out) {
    __shared__ __align__(16) short xls[10 * 272 * 8];   // slot = row*272 + xi*8 + s
    __shared__ __align__(16) short wls[9 * 256 * 8];    // slot = tap*256 + co_l*8 + s

    int b = blockIdx.x;
    int xt = blockIdx.y & 3, cog = blockIdx.y >> 2;
    int ys = blockIdx.z;
    int x0 = xt * 32, y0 = ys * 8;
    int t = threadIdx.x;
    int l = t & 63, w = t >> 6;
    int xq = w & 1, rh = w >> 1;
    int l15 = l & 15, lg = l >> 4;

    const float* xb = x + ((size_t)b * 64) * NPIX;
    const short* wTb = wT + (size_t)b * KEL + cog * 2048;   // 32-co slice per tap

    // ---- stage wls: 9 taps x 32 co x 64 ci (linear DMA, wT pre-swizzled) ----
    #pragma unroll
    for (int it = 0; it < 9; it++) {
        __builtin_amdgcn_global_load_lds(
            (const __attribute__((address_space(1))) void*)(wTb + (size_t)it * 4096 + t * 8),
            (__attribute__((address_space(3))) void*)(wls + (it * 256 + (t & ~63)) * 8),
            16, 0, 0);
    }

    // ---- stage x: 10 rows x 34 xi x 8 cig, direct from NCHW f32 ----
    #pragma unroll
    for (int it = 0; it < 11; it++) {
        int e = it * 256 + t;
        if (e < 2720) {
            int lr = e / 272;
            int rem = e - lr * 272;
            int cig = rem / 34;
            int xi = rem - cig * 34;
            int y = y0 - 1 + lr;
            int gx = x0 - 1 + xi;
            short8 o = {0, 0, 0, 0, 0, 0, 0, 0};
            if ((unsigned)y < 128u && (unsigned)gx < 128u) {
                const float* p = xb + (size_t)(cig * 8) * NPIX + y * 128 + gx;
                #pragma unroll
                for (int c = 0; c < 8; c++) o[c] = bf16_of(p[(size_t)c * NPIX]);
            }
            *(short8*)&xls[(lr * 272 + xi * 8 + (cig ^ (xi & 7))) * 8] = o;
        }
    }
    asm volatile("s_waitcnt vmcnt(0)" ::: "memory");
    __syncthreads();

    f32x4 acc[2][4];                      // [co-frag f][row r]
    #pragma unroll
    for (int f = 0; f < 2; f++)
        #pragma unroll
        for (int r = 0; r < 4; r++) acc[f][r] = (f32x4){0.f, 0.f, 0.f, 0.f};

    #pragma unroll
    for (int kp = 0; kp < 2; kp++) {
        int sig = kp * 4 + lg;
        int pa = sig ^ (l15 & 7);
        #pragma unroll
        for (int tap = 0; tap < 9; tap++) {
            const int dy = tap / 3, dx = tap % 3;
            short8 a0 = *(const short8*)&wls[(tap * 256 + l15 * 8 + pa) * 8];
            short8 a1 = *(const short8*)&wls[(tap * 256 + (16 + l15) * 8 + pa) * 8];
            int xi = xq * 16 + l15 + dx;                 // 0..33
            int sw = sig ^ (xi & 7);
            #pragma unroll
            for (int r = 0; r < 4; r++) {
                int row = rh * 4 + r + dy;               // 0..9
                short8 bf = *(const short8*)&xls[(row * 272 + xi * 8 + sw) * 8];
                acc[0][r] = __builtin_amdgcn_mfma_f32_16x16x32_bf16(a0, bf, acc[0][r], 0, 0, 0);
                acc[1][r] = __builtin_amdgcn_mfma_f32_16x16x32_bf16(a1, bf, acc[1][r], 0, 0, 0);
            }
        }
    }

    // ---- store: 2 co-frags x 4 regs x 4 rows x 16 px ----
    #pragma unroll
    for (int f = 0; f < 2; f++) {
        #pragma unroll
        for (int reg = 0; reg < 4; reg++) {
            float* ob = out + ((size_t)(b * 64 + cog * 32 + f * 16 + lg * 4 + reg)) * NPIX
                            + (y0 + rh * 4) * 128 + x0 + xq * 16 + l15;
            #pragma unroll
            for (int r = 0; r < 4; r++)
                ob[r * 128] = acc[f][r][reg];
        }
    }
}

extern "C" void kernel_launch(void* const* d_in, const int* in_sizes, int n_in,
                              void* d_out, int out_size, void* d_ws, size_t ws_size,
                              hipStream_t stream) {
    const float* x  = (const float*)d_in[0];
    const float* w1 = (const float*)d_in[1];
    const float* b1 = (const float*)d_in[2];
    const float* w2 = (const float*)d_in[3];
    const float* b2 = (const float*)d_in[4];
    float* out = (float*)d_out;

    float* part = (float*)d_ws;                                   // 128 KB
    short* wT = (short*)((char*)d_ws + 131072);                   // 1.18 MB

    stats_k<<<dim3(B_, 8, 16), 256, 0, stream>>>(x, part);
    kern_gen<<<dim3(288), 256, 0, stream>>>(part, w1, b1, w2, b2, wT);
    conv_mfma<<<dim3(B_, 8, 16), 256, 0, stream>>>(x, wT, out);
}

// Round 17
// 66.762 us; speedup vs baseline: 1.0413x; 1.0387x over previous
//
#include <hip/hip_runtime.h>
#include <hip/hip_bf16.h>

// x:[16,64,128,128] f32 -> stats -> MLP -> per-sample kern[64,64,3,3] -> conv(pad=1)
// R17: xT re-laid out as [b][cig(8)][y(128)][x(130)][ci(8)] bf16 -- ci-group is
// the OUTER dim, so the transpose writes contiguous 2KB/row (100% coalesced;
// fixes the 25%-efficient strided-16B writes that cost ~28us in R2-R15).
// Conv = R13 verbatim (proven: 0 bank conflicts, 80KB LDS, 2 resident
// blocks/CU); only the DMA source address maps to the new plane layout.
// wT layout: [b][tap(9)][co(64)][64 ci, slot s at s^(co&7)] (R13-verified).

#define B_ 16
#define NPIX 16384
#define KEL 36864
#define XPS 133120          // plane stride: 128 y * 1040 shorts
#define XRS 1040            // row stride: 130 x * 8 ci shorts

typedef __attribute__((ext_vector_type(4))) float f32x4;
typedef __attribute__((ext_vector_type(8))) short short8;

static __device__ __forceinline__ short bf16_of(float f) {
    __hip_bfloat16 h = __float2bfloat16(f);
    return *reinterpret_cast<short*>(&h);
}

// ---------- Kernel 1: transpose x -> xT [b][cig][y][130][8] + partial stats ----------
// grid (b=16, cig=8, pt=16), 256 thr: 8 rows x 128 x x 8 ci. Writes are
// contiguous 16B x 4 per thread, 2KB per row -> fully coalesced.
__global__ __launch_bounds__(256) void xpose_stats(const float* __restrict__ x,
                                                   short* __restrict__ xT,
                                                   float* __restrict__ part) {
    int b = blockIdx.x, cig = blockIdx.y, pt = blockIdx.z;
    int t = threadIdx.x;
    int y = pt * 8 + (t >> 5);
    int x0 = (t & 31) * 4;

    const float* xb = x + ((size_t)(b * 64 + cig * 8)) * NPIX;
    short* xTp = xT + ((size_t)(b * 8 + cig)) * XPS;

    float s[8], ss[8];
    f32x4 v[8];
    #pragma unroll
    for (int c = 0; c < 8; c++) {
        v[c] = *(const f32x4*)(xb + (size_t)c * NPIX + y * 128 + x0);
        s[c]  = v[c][0] + v[c][1] + v[c][2] + v[c][3];
        ss[c] = v[c][0]*v[c][0] + v[c][1]*v[c][1] + v[c][2]*v[c][2] + v[c][3]*v[c][3];
    }
    #pragma unroll
    for (int xi = 0; xi < 4; xi++) {
        short8 o;
        #pragma unroll
        for (int c = 0; c < 8; c++) o[c] = bf16_of(v[c][xi]);
        *(short8*)(xTp + (size_t)y * XRS + (x0 + xi + 1) * 8) = o;
    }
    // zero halo cols x=0 and x=129 for this block's 8 rows
    if (t < 16) {
        int y2 = pt * 8 + (t & 7);
        int col = (t & 8) ? 129 : 0;
        short8 z = {0, 0, 0, 0, 0, 0, 0, 0};
        *(short8*)(xTp + (size_t)y2 * XRS + col * 8) = z;
    }

    __shared__ float red[4][16];
    int lane = t & 63, w = t >> 6;
    #pragma unroll
    for (int c = 0; c < 8; c++) {
        float a = s[c], q = ss[c];
        for (int off = 32; off; off >>= 1) { a += __shfl_down(a, off); q += __shfl_down(q, off); }
        if (lane == 0) { red[w][c * 2] = a; red[w][c * 2 + 1] = q; }
    }
    __syncthreads();
    if (t < 16)
        part[((size_t)((b * 8 + cig) * 16 + pt)) * 16 + t] =
            red[0][t] + red[1][t] + red[2][t] + red[3][t];
}

// ---------- Kernel 2: w2 read once per j; grid 288, thread = (j, b-half) ----------
__global__ __launch_bounds__(256) void kern_gen(const float* __restrict__ part,
                                                const float* __restrict__ w1,
                                                const float* __restrict__ b1,
                                                const float* __restrict__ w2,
                                                const float* __restrict__ b2,
                                                short* __restrict__ wT) {
    __shared__ float st[16][128];
    __shared__ float hT[32][16];
    int t = threadIdx.x;

    for (int id = t; id < 1024; id += 256) {       // stats for all (b, ci)
        int b = id >> 6, ci = id & 63;
        const float* pb = part + ((size_t)((b * 8 + (ci >> 3)) * 16)) * 16 + (ci & 7) * 2;
        float s = 0.f, q = 0.f;
        #pragma unroll
        for (int p = 0; p < 16; p++) { s += pb[p * 16]; q += pb[p * 16 + 1]; }
        float mean = s * (1.f / NPIX);
        float var = fmaxf((q - s * mean) * (1.f / (NPIX - 1)), 0.f);
        st[b][ci] = mean;
        st[b][64 + ci] = sqrtf(var);
    }
    __syncthreads();
    for (int id = t; id < 512; id += 256) {        // h for all (b, 32), transposed
        int b = id >> 5, jj = id & 31;
        float acc = b1[jj];
        for (int i = 0; i < 128; i++) acc += st[b][i] * w1[i * 32 + jj];
        hT[jj][b] = fmaxf(acc, 0.f);
    }
    __syncthreads();

    int j = blockIdx.x * 128 + (t & 127);
    int bh = t >> 7;                               // b-half 0/1
    float wv[32];
    #pragma unroll
    for (int i = 0; i < 32; i++) wv[i] = w2[(size_t)i * KEL + j];
    float bv = b2[j];

    float acc[8];
    #pragma unroll
    for (int k = 0; k < 8; k++) acc[k] = bv;
    #pragma unroll
    for (int i = 0; i < 32; i++) {
        float wvi = wv[i];
        const f32x4* hr = (const f32x4*)&hT[i][bh * 8];
        #pragma unroll
        for (int q4 = 0; q4 < 2; q4++) {
            f32x4 hq = hr[q4];
            acc[q4 * 4 + 0] += hq[0] * wvi;
            acc[q4 * 4 + 1] += hq[1] * wvi;
            acc[q4 * 4 + 2] += hq[2] * wvi;
            acc[q4 * 4 + 3] += hq[3] * wvi;
        }
    }

    // j = (co*64+ci)*9 + tap; pre-swizzled: [tap][co][ (ci>>3)^(co&7) slot ]
    int co = j / 576;
    int rem = j - co * 576;
    int ci = rem / 9;
    int tap = rem - ci * 9;
    size_t dst = (size_t)tap * 4096 + co * 64 + ((((ci >> 3) ^ (co & 7)) << 3) | (ci & 7));
    #pragma unroll
    for (int k = 0; k < 8; k++)
        wT[(size_t)(bh * 8 + k) * KEL + dst] = bf16_of(acc[k]);
}

// ---------- Kernel 3: conv via MFMA (R13 verbatim; new DMA source mapping) ----------
// grid (b=16, xt+4*cog=8, ys=16) = 2048 blocks (8/CU, 2 resident), 256 thr (4 waves).
// Block: 32 px x 8 rows x 32 co. Wave (xq=w&1, rh=w>>1): 16 px x 4 rows x 32 co.
// LDS: xls 10 rows x 272 slots x 16B (43520 B) + wls 9 x 256 x 16B (36864 B) = 80384 B.
// LDS slot (xi, p) holds ci-chunk p^(xi&7): DMA source = plane (p^(xi&7)).
__global__ __launch_bounds__(256, 2) void conv_mfma(const short* __restrict__ xT,
                                                    const short* __restrict__ wT,
                                                    float* __restrict__ out) {
    __shared__ __align__(16) short xls[10 * 272 * 8];   // slot = row*272 + xi*8 + s
    __shared__ __align__(16) short wls[9 * 256 * 8];    // slot = tap*256 + co_l*8 + s

    int b = blockIdx.x;
    int xt = blockIdx.y & 3, cog = blockIdx.y >> 2;
    int ys = blockIdx.z;
    int x0 = xt * 32, y0 = ys * 8;
    int t = threadIdx.x;
    int l = t & 63, w = t >> 6;
    int xq = w & 1, rh = w >> 1;
    int l15 = l & 15, lg = l >> 4;

    const short* xTb = xT + (size_t)b * 8 * XPS;
    const short* wTb = wT + (size_t)b * KEL + cog * 2048;   // 32-co slice within each tap

    // ---- stage wls: 9 taps x 32 co x 64 ci (linear DMA, wT pre-swizzled) ----
    #pragma unroll
    for (int it = 0; it < 9; it++) {
        __builtin_amdgcn_global_load_lds(
            (const __attribute__((address_space(1))) void*)(wTb + (size_t)it * 4096 + t * 8),
            (__attribute__((address_space(3))) void*)(wls + (it * 256 + (t & ~63)) * 8),
            16, 0, 0);
    }
    // ---- stage x rows y0-1 .. y0+8 into slots 0..9 ----
    #pragma unroll
    for (int lr = 0; lr < 10; lr++) {
        int y = y0 - 1 + lr;
        if (y < 0 || y > 127) {
            short8 z8 = {0, 0, 0, 0, 0, 0, 0, 0};
            #pragma unroll
            for (int it = 0; it < 2; it++) {
                int e = it * 256 + t;
                if (e < 272) *(short8*)(xls + (lr * 272 + e) * 8) = z8;
            }
        } else {
            #pragma unroll
            for (int it = 0; it < 2; it++) {
                int e = it * 256 + t;
                if (e < 272) {
                    int xi = e >> 3, s = e & 7;
                    int plane = s ^ (xi & 7);
                    const short* src = xTb + (size_t)plane * XPS
                        + (size_t)y * XRS + (x0 + xi) * 8;
                    __builtin_amdgcn_global_load_lds(
                        (const __attribute__((address_space(1))) void*)src,
                        (__attribute__((address_space(3))) void*)
                            (xls + (lr * 272 + it * 256 + (t & ~63)) * 8),
                        16, 0, 0);
                }
            }
        }
    }
    asm volatile("s_waitcnt vmcnt(0)" ::: "memory");
    __syncthreads();

    f32x4 acc[2][4];                      // [co-frag f][row r]
    #pragma unroll
    for (int f = 0; f < 2; f++)
        #pragma unroll
        for (int r = 0; r < 4; r++) acc[f][r] = (f32x4){0.f, 0.f, 0.f, 0.f};

    #pragma unroll
    for (int kp = 0; kp < 2; kp++) {
        int sig = kp * 4 + lg;
        int pa = sig ^ (l15 & 7);
        #pragma unroll
        for (int tap = 0; tap < 9; tap++) {
            const int dy = tap / 3, dx = tap % 3;
            short8 a0 = *(const short8*)&wls[(tap * 256 + l15 * 8 + pa) * 8];
            short8 a1 = *(const short8*)&wls[(tap * 256 + (16 + l15) * 8 + pa) * 8];
            int xi = xq * 16 + l15 + dx;                 // 0..33
            int sw = sig ^ (xi & 7);
            #pragma unroll
            for (int r = 0; r < 4; r++) {
                int row = rh * 4 + r + dy;               // 0..9
                short8 bf = *(const short8*)&xls[(row * 272 + xi * 8 + sw) * 8];
                acc[0][r] = __builtin_amdgcn_mfma_f32_16x16x32_bf16(a0, bf, acc[0][r], 0, 0, 0);
                acc[1][r] = __builtin_amdgcn_mfma_f32_16x16x32_bf16(a1, bf, acc[1][r], 0, 0, 0);
            }
        }
    }

    // ---- store: 2 co-frags x 4 regs x 4 rows x 16 px ----
    #pragma unroll
    for (int f = 0; f < 2; f++) {
        #pragma unroll
        for (int reg = 0; reg < 4; reg++) {
            float* ob = out + ((size_t)(b * 64 + cog * 32 + f * 16 + lg * 4 + reg)) * NPIX
                            + (y0 + rh * 4) * 128 + x0 + xq * 16 + l15;
            #pragma unroll
            for (int r = 0; r < 4; r++)
                ob[r * 128] = acc[f][r][reg];
        }
    }
}

extern "C" void kernel_launch(void* const* d_in, const int* in_sizes, int n_in,
                              void* d_out, int out_size, void* d_ws, size_t ws_size,
                              hipStream_t stream) {
    const float* x  = (const float*)d_in[0];
    const float* w1 = (const float*)d_in[1];
    const float* b1 = (const float*)d_in[2];
    const float* w2 = (const float*)d_in[3];
    const float* b2 = (const float*)d_in[4];
    float* out = (float*)d_out;

    float* part = (float*)d_ws;                                   // 128 KB
    short* wT = (short*)((char*)d_ws + 131072);                   // 1.18 MB
    short* xT = (short*)((char*)d_ws + 131072 + 1179648);         // 34.1 MB

    xpose_stats<<<dim3(B_, 8, 16), 256, 0, stream>>>(x, xT, part);
    kern_gen<<<dim3(288), 256, 0, stream>>>(part, w1, b1, w2, b2, wT);
    conv_mfma<<<dim3(B_, 8, 16), 256, 0, stream>>>(xT, wT, out);
}